// Round 1
// baseline (437.355 us; speedup 1.0000x reference)
//
#include <hip/hip_runtime.h>

#define IMG_H 512
#define IMG_W 512
#define CH_STRIDE (IMG_H*IMG_W)     // 262144
#define IMG_STRIDE (3*CH_STRIDE)

// ---------------- block reduction helper (256 threads = 4 waves) ----------
__device__ __forceinline__ float block_sum(float v, float* red) {
  #pragma unroll
  for (int o = 32; o > 0; o >>= 1) v += __shfl_down(v, o, 64);
  __syncthreads();
  if ((threadIdx.x & 63) == 0) red[threadIdx.x >> 6] = v;
  __syncthreads();
  return red[0] + red[1] + red[2] + red[3];
}

// ---------------- kernel 1: con + sobel-gradient + color partials ---------
#define T1W 64
#define T1H 16
#define R1W (T1W+2)   // 66
#define R1H (T1H+2)   // 18
#define R1N (R1W*R1H) // 1188

__device__ __forceinline__ void sobel3(const float* f, int o, float& gx, float& gy) {
  float a = f[o - R1W - 1], b = f[o - R1W], c = f[o - R1W + 1];
  float d = f[o - 1],                       e = f[o + 1];
  float p = f[o + R1W - 1], q = f[o + R1W], r = f[o + R1W + 1];
  // cross-correlation with Kx=[[-1,0,1],[-2,0,2],[-1,0,1]], Ky=[[1,2,1],[0,0,0],[-1,-2,-1]]
  gx = (c - a) + 2.f*(e - d) + (r - p);
  gy = (a + 2.f*b + c) - (p + 2.f*q + r);
}

__global__ __launch_bounds__(256) void k_point_sobel(
    const float* __restrict__ vis, const float* __restrict__ ir,
    const float* __restrict__ fuse, float* __restrict__ partial)
{
  __shared__ float s[9*R1N];
  __shared__ float red[4];
  const int tid = threadIdx.x;
  const int n  = blockIdx.z;
  const int x0 = blockIdx.x * T1W - 1;
  const int y0 = blockIdx.y * T1H - 1;

  for (int i = tid; i < 9*R1N; i += 256) {
    int f  = i / R1N;
    int r  = i - f*R1N;
    int ly = r / R1W;
    int lx = r - ly*R1W;
    int gy = y0 + ly, gx = x0 + lx;
    float v = 0.f;
    if ((unsigned)gx < IMG_W && (unsigned)gy < IMG_H) {
      int tensor = f / 3, c = f - tensor*3;
      const float* bp = (tensor == 0) ? vis : ((tensor == 1) ? ir : fuse);
      v = bp[(n*3 + c)*CH_STRIDE + gy*IMG_W + gx];
    }
    s[i] = v;
  }
  __syncthreads();

  float con=0.f, gxs=0.f, gys=0.f, cbs=0.f, crs=0.f;
  #pragma unroll
  for (int j = 0; j < 4; ++j) {
    int p  = tid + 256*j;           // 0..1023
    int ox = p & (T1W-1), oy = p >> 6;
    int o  = (oy+1)*R1W + (ox+1);
    float pv[3], pi[3], pf[3];
    #pragma unroll
    for (int c = 0; c < 3; ++c) {
      const float* sv = s + c*R1N;
      const float* si = s + (3+c)*R1N;
      const float* sf = s + (6+c)*R1N;
      float vc = sv[o], ic = si[o], fc = sf[o];
      pv[c]=vc; pi[c]=ic; pf[c]=fc;
      con += fabsf(fc - fmaxf(vc, ic));
      float vgx,vgy,igx,igy,fgx,fgy;
      sobel3(sv, o, vgx, vgy);
      sobel3(si, o, igx, igy);
      sobel3(sf, o, fgx, fgy);
      gxs += fabsf(fgx - fmaxf(vgx, igx));
      gys += fabsf(fgy - fmaxf(vgy, igy));
    }
    float Yf = 0.299f*pf[0] + 0.587f*pf[1] + 0.114f*pf[2];
    float Yv = 0.299f*pv[0] + 0.587f*pv[1] + 0.114f*pv[2];
    crs += fabsf((pf[0]-Yf)*0.713f - (pv[0]-Yv)*0.713f);
    cbs += fabsf((pf[2]-Yf)*0.564f - (pv[2]-Yv)*0.564f);
  }

  float r0 = block_sum(con, red);
  float r1 = block_sum(gxs, red);
  float r2 = block_sum(gys, red);
  float r3 = block_sum(cbs, red);
  float r4 = block_sum(crs, red);
  if (tid == 0) {
    int bid = (blockIdx.z*32 + blockIdx.y)*8 + blockIdx.x;   // grid (8,32,16)
    float* p = partial + bid*5;
    p[0]=r0; p[1]=r1; p[2]=r2; p[3]=r3; p[4]=r4;
  }
}

// ---------------- kernel 2: SSIM partials (one (n,pair) per blockIdx.z) ---
#define T2W 64
#define T2H 32
#define R2W (T2W+10)  // 74
#define R2H (T2H+10)  // 42
#define R2N (R2W*R2H) // 3108
#define HN  (T2W*R2H) // 2688

#define CONV_PASS(EXPR, DST) \
  for (int q = tid; q < HN; q += 256) { \
    int base = (q >> 6)*R2W + (q & 63); \
    float acc = 0.f; \
    _Pragma("unroll") \
    for (int k = 0; k < 11; ++k) { \
      float a = sx[base+k]; float b = sy[base+k]; (void)a; (void)b; \
      acc = fmaf(g[k], (EXPR), acc); \
    } \
    hbuf[q] = acc; \
  } \
  __syncthreads(); \
  _Pragma("unroll") \
  for (int j = 0; j < 8; ++j) { \
    int p = tid + 256*j; \
    int ox = p & 63, oy = p >> 6; \
    float acc = 0.f; \
    _Pragma("unroll") \
    for (int k = 0; k < 11; ++k) acc = fmaf(g[k], hbuf[(oy+k)*T2W + ox], acc); \
    DST[j] = acc; \
  } \
  __syncthreads();

__global__ __launch_bounds__(256) void k_ssim(
    const float* __restrict__ vis, const float* __restrict__ ir,
    const float* __restrict__ fuse, float* __restrict__ partial2)
{
  __shared__ float sx[R2N];
  __shared__ float sy[R2N];
  __shared__ float hbuf[HN];
  __shared__ float red[4];
  const int tid = threadIdx.x;
  const int z = blockIdx.z;            // n*4 + pair
  const int n = z >> 2, pair = z & 3;
  const int x0 = blockIdx.x*T2W - 5;
  const int y0 = blockIdx.y*T2H - 5;

  // Gaussian weights: fp64-accurate unnormalized exp(-d^2/4.5), normalized here
  float g[11];
  {
    const float gu[6] = {0.00386592014f, 0.02856550078f, 0.13533528324f,
                         0.41111229050f, 0.80073740292f, 1.0f};
    float gs = 0.f;
    #pragma unroll
    for (int i = 0; i < 11; ++i) { g[i] = gu[i < 6 ? i : 10 - i]; gs += g[i]; }
    #pragma unroll
    for (int i = 0; i < 11; ++i) g[i] /= gs;
  }

  for (int i = tid; i < R2N; i += 256) {
    int ly = i / R2W, lx = i - ly*R2W;
    int gy = y0 + ly, gx = x0 + lx;
    float xa = 0.f, ya = 0.f;
    if ((unsigned)gx < IMG_W && (unsigned)gy < IMG_H) {
      int off = gy*IMG_W + gx;
      if (pair < 3) {
        xa = vis [(n*3 + pair)*CH_STRIDE + off];
        ya = fuse[(n*3 + pair)*CH_STRIDE + off];
      } else {
        xa = ir[n*IMG_STRIDE + off];                 // Y_ir = ir channel 0
        const float* fb = fuse + n*IMG_STRIDE + off;
        ya = 0.2989f*fb[0] + 0.587f*fb[CH_STRIDE] + 0.114f*fb[2*CH_STRIDE];
      }
    }
    sx[i] = xa; sy[i] = ya;
  }
  __syncthreads();

  float m1[8], m2[8], e11[8], e22[8], e12[8];
  CONV_PASS(a,   m1)
  CONV_PASS(b,   m2)
  CONV_PASS(a*a, e11)
  CONV_PASS(b*b, e22)
  CONV_PASS(a*b, e12)

  float ss = 0.f;
  #pragma unroll
  for (int j = 0; j < 8; ++j) {
    float mu1 = m1[j], mu2 = m2[j];
    float mu1s = mu1*mu1, mu2s = mu2*mu2, mu12 = mu1*mu2;
    float s1 = e11[j]-mu1s, s2 = e22[j]-mu2s, s12 = e12[j]-mu12;
    float num = (2.f*mu12 + 1e-4f) * (2.f*s12 + 9e-4f);
    float den = (mu1s + mu2s + 1e-4f) * (s1 + s2 + 9e-4f);
    ss += num / den;
  }
  float tot = block_sum(ss, red);
  if (tid == 0) {
    int bid2 = (z*16 + blockIdx.y)*8 + blockIdx.x;   // grid (8,16,64)
    partial2[bid2] = tot;
  }
}

// ---------------- kernel 3: final combine ---------------------------------
__global__ __launch_bounds__(256) void k_final(
    const float* __restrict__ p1, const float* __restrict__ p2,
    float* __restrict__ out)
{
  __shared__ float red[4];
  const int tid = threadIdx.x;
  float con=0.f,gxs=0.f,gys=0.f,cbs=0.f,crs=0.f,srgb=0.f,sir=0.f;
  for (int i = tid; i < 4096; i += 256) {
    const float* p = p1 + i*5;
    con += p[0]; gxs += p[1]; gys += p[2]; cbs += p[3]; crs += p[4];
  }
  for (int i = tid; i < 8192; i += 256) {
    float v = p2[i];
    if (((i >> 7) & 3) == 3) sir += v; else srgb += v;
  }
  con  = block_sum(con,  red);
  gxs  = block_sum(gxs,  red);
  gys  = block_sum(gys,  red);
  cbs  = block_sum(cbs,  red);
  crs  = block_sum(crs,  red);
  srgb = block_sum(srgb, red);
  sir  = block_sum(sir,  red);
  if (tid == 0) {
    const float N3 = 16.f*3.f*512.f*512.f;
    const float N1 = 16.f*512.f*512.f;
    float con_loss  = con / N3;
    float grad_loss = 0.5f*(gxs/N3) + 0.5f*(gys/N3);
    float color_loss = cbs/N1 + crs/N1;
    float ssim_loss = 1.f - (srgb/N3 + sir/N1)*0.5f;
    out[0] = 0.5f*con_loss + 0.2f*grad_loss + color_loss + 0.1f*ssim_loss;
  }
}

extern "C" void kernel_launch(void* const* d_in, const int* in_sizes, int n_in,
                              void* d_out, int out_size, void* d_ws, size_t ws_size,
                              hipStream_t stream) {
  (void)in_sizes; (void)n_in; (void)out_size; (void)ws_size;
  const float* vis  = (const float*)d_in[0];
  const float* ir   = (const float*)d_in[1];
  const float* fuse = (const float*)d_in[2];
  float* out = (float*)d_out;
  float* p1 = (float*)d_ws;        // 4096*5 floats, all slots written every launch
  float* p2 = p1 + 4096*5;         // 8192 floats, all slots written every launch

  dim3 b(256,1,1);
  dim3 g1(8, 32, 16);
  k_point_sobel<<<g1, b, 0, stream>>>(vis, ir, fuse, p1);
  dim3 g2(8, 16, 64);
  k_ssim<<<g2, b, 0, stream>>>(vis, ir, fuse, p2);
  k_final<<<dim3(1,1,1), b, 0, stream>>>(p1, p2, out);
}

// Round 2
// 430.686 us; speedup vs baseline: 1.0155x; 1.0155x over previous
//
#include <hip/hip_runtime.h>

#define IMG_H 512
#define IMG_W 512
#define CH_STRIDE (IMG_H*IMG_W)     // 262144
#define IMG_STRIDE (3*CH_STRIDE)

using f4 = __attribute__((ext_vector_type(4))) float;

// ---------------- block reduction helper (256 threads = 4 waves) ----------
__device__ __forceinline__ float block_sum(float v, float* red) {
  #pragma unroll
  for (int o = 32; o > 0; o >>= 1) v += __shfl_down(v, o, 64);
  __syncthreads();
  if ((threadIdx.x & 63) == 0) red[threadIdx.x >> 6] = v;
  __syncthreads();
  return red[0] + red[1] + red[2] + red[3];
}

// ---------------- kernel 1: con + sobel-gradient + color partials ---------
// Tile 64x16, halo 1. LDS row stride padded to 68 for 16B-aligned b128 reads.
#define T1W 64
#define T1H 16
#define R1W 68        // 66 valid cols (x0-1 .. x0+64), 2 pad
#define R1H 18
#define R1N (R1W*R1H) // 1224

__global__ __launch_bounds__(256) void k_point_sobel(
    const float* __restrict__ vis, const float* __restrict__ ir,
    const float* __restrict__ fuse, float* __restrict__ partial)
{
  __shared__ __align__(16) float s[9*R1N];
  __shared__ float red[4];
  const int tid = threadIdx.x;
  const int n  = blockIdx.z;
  const int x0 = blockIdx.x * T1W;
  const int y0 = blockIdx.y * T1H;

  // stage 9 fields (vis0-2, ir0-2, fuse0-2) with halo, zero-padded
  #pragma unroll
  for (int f = 0; f < 9; ++f) {
    const float* bp = (f < 3) ? vis : ((f < 6) ? ir : fuse);
    const float* base = bp + (n*3 + (f % 3))*CH_STRIDE;
    for (int i = tid; i < R1N; i += 256) {
      int ly = i / R1W, lx = i - ly*R1W;
      int gy = y0 - 1 + ly, gx = x0 - 1 + lx;
      float v = 0.f;
      if ((unsigned)gx < IMG_W && (unsigned)gy < IMG_H)
        v = base[gy*IMG_W + gx];
      s[f*R1N + i] = v;
    }
  }
  __syncthreads();

  // each thread: 4 adjacent x pixels
  const int ox = (tid & 15) * 4;     // 0..60
  const int oy = tid >> 4;           // 0..15
  float con=0.f, gxs=0.f, gys=0.f, cbs=0.f, crs=0.f;
  float pv[3][4], pf[3][4];

  #pragma unroll
  for (int c = 0; c < 3; ++c) {
    float cen[3][4], gxv[3][4], gyv[3][4];
    #pragma unroll
    for (int t = 0; t < 3; ++t) {
      const float* sf = s + (t*3 + c)*R1N;
      float r0[8], r1[8], r2[8];
      {
        f4 a = *(const f4*)&sf[(oy+0)*R1W + ox], b = *(const f4*)&sf[(oy+0)*R1W + ox + 4];
        r0[0]=a.x; r0[1]=a.y; r0[2]=a.z; r0[3]=a.w; r0[4]=b.x; r0[5]=b.y; r0[6]=b.z; r0[7]=b.w;
      }
      {
        f4 a = *(const f4*)&sf[(oy+1)*R1W + ox], b = *(const f4*)&sf[(oy+1)*R1W + ox + 4];
        r1[0]=a.x; r1[1]=a.y; r1[2]=a.z; r1[3]=a.w; r1[4]=b.x; r1[5]=b.y; r1[6]=b.z; r1[7]=b.w;
      }
      {
        f4 a = *(const f4*)&sf[(oy+2)*R1W + ox], b = *(const f4*)&sf[(oy+2)*R1W + ox + 4];
        r2[0]=a.x; r2[1]=a.y; r2[2]=a.z; r2[3]=a.w; r2[4]=b.x; r2[5]=b.y; r2[6]=b.z; r2[7]=b.w;
      }
      #pragma unroll
      for (int j = 0; j < 4; ++j) {
        gxv[t][j] = (r0[j+2]-r0[j]) + 2.f*(r1[j+2]-r1[j]) + (r2[j+2]-r2[j]);
        gyv[t][j] = (r0[j] + 2.f*r0[j+1] + r0[j+2]) - (r2[j] + 2.f*r2[j+1] + r2[j+2]);
        cen[t][j] = r1[j+1];
      }
    }
    #pragma unroll
    for (int j = 0; j < 4; ++j) {
      con += fabsf(cen[2][j] - fmaxf(cen[0][j], cen[1][j]));
      gxs += fabsf(gxv[2][j] - fmaxf(gxv[0][j], gxv[1][j]));
      gys += fabsf(gyv[2][j] - fmaxf(gyv[0][j], gyv[1][j]));
      pv[c][j] = cen[0][j];
      pf[c][j] = cen[2][j];
    }
  }
  #pragma unroll
  for (int j = 0; j < 4; ++j) {
    float Yf = 0.299f*pf[0][j] + 0.587f*pf[1][j] + 0.114f*pf[2][j];
    float Yv = 0.299f*pv[0][j] + 0.587f*pv[1][j] + 0.114f*pv[2][j];
    crs += fabsf(0.713f*((pf[0][j]-Yf) - (pv[0][j]-Yv)));
    cbs += fabsf(0.564f*((pf[2][j]-Yf) - (pv[2][j]-Yv)));
  }

  float r0 = block_sum(con, red);
  float r1 = block_sum(gxs, red);
  float r2 = block_sum(gys, red);
  float r3 = block_sum(cbs, red);
  float r4 = block_sum(crs, red);
  if (tid == 0) {
    int bid = (blockIdx.z*32 + blockIdx.y)*8 + blockIdx.x;   // grid (8,32,16)
    partial[0*4096 + bid] = r0;
    partial[1*4096 + bid] = r1;
    partial[2*4096 + bid] = r2;
    partial[3*4096 + bid] = r3;
    partial[4*4096 + bid] = r4;
  }
}

// ---------------- kernel 2: SSIM partials (one (n,pair) per blockIdx.z) ---
// Tile 64x32, halo 5. Horizontal conv of 4 fused fields (a, b, a^2+b^2, a*b)
// with 4-wide register window; vertical conv strip-mined (2 rows/thread).
#define T2W 64
#define T2H 32
#define R2W 76        // 74 valid cols (x0-5 .. x0+68), 2 pad (16B-aligned rows)
#define R2H 42
#define R2N (R2W*R2H) // 3192
#define HN2 (T2W*R2H) // 2688

__global__ __launch_bounds__(256) void k_ssim(
    const float* __restrict__ vis, const float* __restrict__ ir,
    const float* __restrict__ fuse, float* __restrict__ partial2)
{
  __shared__ __align__(16) float sx[R2N];
  __shared__ __align__(16) float sy[R2N];
  __shared__ __align__(16) float hA[HN2];
  __shared__ __align__(16) float hB[HN2];
  __shared__ __align__(16) float hP[HN2];
  __shared__ __align__(16) float hQ[HN2];
  __shared__ float red[4];
  const int tid = threadIdx.x;
  const int z = blockIdx.z;            // n*4 + pair
  const int n = z >> 2, pair = z & 3;
  const int x0 = blockIdx.x*T2W;
  const int y0 = blockIdx.y*T2H;

  // Gaussian weights (fp64-accurate unnormalized exp(-d^2/4.5), normalized)
  float g[11];
  {
    const float gu[6] = {0.00386592014f, 0.02856550078f, 0.13533528324f,
                         0.41111229050f, 0.80073740292f, 1.0f};
    float gs = 0.f;
    #pragma unroll
    for (int i = 0; i < 11; ++i) { g[i] = gu[i < 6 ? i : 10 - i]; gs += g[i]; }
    #pragma unroll
    for (int i = 0; i < 11; ++i) g[i] /= gs;
  }

  // stage (zero-padded)
  if (pair < 3) {
    const float* xb = vis  + (n*3 + pair)*CH_STRIDE;
    const float* yb = fuse + (n*3 + pair)*CH_STRIDE;
    for (int i = tid; i < R2N; i += 256) {
      int ly = i / R2W, lx = i - ly*R2W;
      int gy = y0 - 5 + ly, gx = x0 - 5 + lx;
      float xa = 0.f, ya = 0.f;
      if ((unsigned)gx < IMG_W && (unsigned)gy < IMG_H && lx < 74) {
        int off = gy*IMG_W + gx;
        xa = xb[off]; ya = yb[off];
      }
      sx[i] = xa; sy[i] = ya;
    }
  } else {
    const float* xb = ir   + n*IMG_STRIDE;
    const float* fb = fuse + n*IMG_STRIDE;
    for (int i = tid; i < R2N; i += 256) {
      int ly = i / R2W, lx = i - ly*R2W;
      int gy = y0 - 5 + ly, gx = x0 - 5 + lx;
      float xa = 0.f, ya = 0.f;
      if ((unsigned)gx < IMG_W && (unsigned)gy < IMG_H && lx < 74) {
        int off = gy*IMG_W + gx;
        xa = xb[off];
        ya = 0.2989f*fb[off] + 0.587f*fb[off + CH_STRIDE] + 0.114f*fb[off + 2*CH_STRIDE];
      }
      sx[i] = xa; sy[i] = ya;
    }
  }
  __syncthreads();

  // horizontal pass: 672 groups (42 rows x 16 xgroups), 4-wide window
  for (int gi = tid; gi < R2H*16; gi += 256) {
    int row = gi >> 4, ox = (gi & 15) * 4;
    int base = row*R2W + ox;
    float wa[16], wb[16], wp[16], wq[16];
    {
      f4 a0 = *(const f4*)&sx[base],    a1 = *(const f4*)&sx[base+4];
      f4 a2 = *(const f4*)&sx[base+8],  a3 = *(const f4*)&sx[base+12];
      f4 b0 = *(const f4*)&sy[base],    b1 = *(const f4*)&sy[base+4];
      f4 b2 = *(const f4*)&sy[base+8],  b3 = *(const f4*)&sy[base+12];
      wa[0]=a0.x; wa[1]=a0.y; wa[2]=a0.z; wa[3]=a0.w;
      wa[4]=a1.x; wa[5]=a1.y; wa[6]=a1.z; wa[7]=a1.w;
      wa[8]=a2.x; wa[9]=a2.y; wa[10]=a2.z; wa[11]=a2.w;
      wa[12]=a3.x; wa[13]=a3.y; wa[14]=a3.z; wa[15]=a3.w;
      wb[0]=b0.x; wb[1]=b0.y; wb[2]=b0.z; wb[3]=b0.w;
      wb[4]=b1.x; wb[5]=b1.y; wb[6]=b1.z; wb[7]=b1.w;
      wb[8]=b2.x; wb[9]=b2.y; wb[10]=b2.z; wb[11]=b2.w;
      wb[12]=b3.x; wb[13]=b3.y; wb[14]=b3.z; wb[15]=b3.w;
    }
    #pragma unroll
    for (int i = 0; i < 14; ++i) {   // taps use indices 0..13 only
      wp[i] = fmaf(wa[i], wa[i], wb[i]*wb[i]);
      wq[i] = wa[i]*wb[i];
    }
    float hA4[4]={0,0,0,0}, hB4[4]={0,0,0,0}, hP4[4]={0,0,0,0}, hQ4[4]={0,0,0,0};
    #pragma unroll
    for (int k = 0; k < 11; ++k) {
      float gk = g[k];
      #pragma unroll
      for (int j = 0; j < 4; ++j) {
        hA4[j] = fmaf(gk, wa[k+j], hA4[j]);
        hB4[j] = fmaf(gk, wb[k+j], hB4[j]);
        hP4[j] = fmaf(gk, wp[k+j], hP4[j]);
        hQ4[j] = fmaf(gk, wq[k+j], hQ4[j]);
      }
    }
    int ob = row*T2W + ox;
    *(f4*)&hA[ob] = f4{hA4[0], hA4[1], hA4[2], hA4[3]};
    *(f4*)&hB[ob] = f4{hB4[0], hB4[1], hB4[2], hB4[3]};
    *(f4*)&hP[ob] = f4{hP4[0], hP4[1], hP4[2], hP4[3]};
    *(f4*)&hQ[ob] = f4{hQ4[0], hQ4[1], hQ4[2], hQ4[3]};
  }
  __syncthreads();

  // vertical pass: 256 strips of 4 wide x 2 rows, streaming 12 hbuf rows
  const int ox = (tid & 15) * 4;
  const int yb2 = (tid >> 4) * 2;    // 0,2,..,30
  float aA0[4]={0,0,0,0}, aA1[4]={0,0,0,0};
  float aB0[4]={0,0,0,0}, aB1[4]={0,0,0,0};
  float aP0[4]={0,0,0,0}, aP1[4]={0,0,0,0};
  float aQ0[4]={0,0,0,0}, aQ1[4]={0,0,0,0};
  #pragma unroll
  for (int r = 0; r < 12; ++r) {
    int rb = (yb2 + r)*T2W + ox;
    f4 fA = *(const f4*)&hA[rb];
    f4 fB = *(const f4*)&hB[rb];
    f4 fP = *(const f4*)&hP[rb];
    f4 fQ = *(const f4*)&hQ[rb];
    if (r < 11) {
      float gk = g[r];
      #pragma unroll
      for (int j = 0; j < 4; ++j) {
        aA0[j] = fmaf(gk, fA[j], aA0[j]);
        aB0[j] = fmaf(gk, fB[j], aB0[j]);
        aP0[j] = fmaf(gk, fP[j], aP0[j]);
        aQ0[j] = fmaf(gk, fQ[j], aQ0[j]);
      }
    }
    if (r >= 1) {
      float gk = g[r-1];
      #pragma unroll
      for (int j = 0; j < 4; ++j) {
        aA1[j] = fmaf(gk, fA[j], aA1[j]);
        aB1[j] = fmaf(gk, fB[j], aB1[j]);
        aP1[j] = fmaf(gk, fP[j], aP1[j]);
        aQ1[j] = fmaf(gk, fQ[j], aQ1[j]);
      }
    }
  }

  float ss = 0.f;
  #pragma unroll
  for (int j = 0; j < 4; ++j) {
    {
      float mu1 = aA0[j], mu2 = aB0[j];
      float mu12 = mu1*mu2, mss = mu1*mu1 + mu2*mu2;
      float s12 = aQ0[j] - mu12, sps = aP0[j] - mss;
      ss += ((2.f*mu12 + 1e-4f)*(2.f*s12 + 9e-4f)) / ((mss + 1e-4f)*(sps + 9e-4f));
    }
    {
      float mu1 = aA1[j], mu2 = aB1[j];
      float mu12 = mu1*mu2, mss = mu1*mu1 + mu2*mu2;
      float s12 = aQ1[j] - mu12, sps = aP1[j] - mss;
      ss += ((2.f*mu12 + 1e-4f)*(2.f*s12 + 9e-4f)) / ((mss + 1e-4f)*(sps + 9e-4f));
    }
  }
  float tot = block_sum(ss, red);
  if (tid == 0) {
    int bid2 = ((pair*16 + n)*16 + blockIdx.y)*8 + blockIdx.x;  // pair-major
    partial2[bid2] = tot;
  }
}

// ---------------- kernel 3: final combine ---------------------------------
__global__ __launch_bounds__(256) void k_final(
    const float* __restrict__ p1, const float* __restrict__ p2,
    float* __restrict__ out)
{
  __shared__ float red[4];
  const int tid = threadIdx.x;
  float s5[5];
  #pragma unroll
  for (int t = 0; t < 5; ++t) {
    float acc = 0.f;
    #pragma unroll
    for (int u = 0; u < 4; ++u) {
      f4 v = *(const f4*)&p1[t*4096 + u*1024 + tid*4];
      acc += (v.x + v.y) + (v.z + v.w);
    }
    s5[t] = acc;
  }
  float srgb = 0.f, sir = 0.f;
  #pragma unroll
  for (int u = 0; u < 8; ++u) {
    f4 v = *(const f4*)&p2[u*1024 + tid*4];
    float sv = (v.x + v.y) + (v.z + v.w);
    if (u < 6) srgb += sv; else sir += sv;
  }
  float con  = block_sum(s5[0], red);
  float gxs  = block_sum(s5[1], red);
  float gys  = block_sum(s5[2], red);
  float cbs  = block_sum(s5[3], red);
  float crs  = block_sum(s5[4], red);
  float sr   = block_sum(srgb,  red);
  float si   = block_sum(sir,   red);
  if (tid == 0) {
    const float N3 = 16.f*3.f*512.f*512.f;
    const float N1 = 16.f*512.f*512.f;
    float con_loss  = con / N3;
    float grad_loss = 0.5f*(gxs/N3) + 0.5f*(gys/N3);
    float color_loss = cbs/N1 + crs/N1;
    float ssim_loss = 1.f - (sr/N3 + si/N1)*0.5f;
    out[0] = 0.5f*con_loss + 0.2f*grad_loss + color_loss + 0.1f*ssim_loss;
  }
}

extern "C" void kernel_launch(void* const* d_in, const int* in_sizes, int n_in,
                              void* d_out, int out_size, void* d_ws, size_t ws_size,
                              hipStream_t stream) {
  (void)in_sizes; (void)n_in; (void)out_size; (void)ws_size;
  const float* vis  = (const float*)d_in[0];
  const float* ir   = (const float*)d_in[1];
  const float* fuse = (const float*)d_in[2];
  float* out = (float*)d_out;
  float* p1 = (float*)d_ws;        // 5*4096 floats, planar, all written every launch
  float* p2 = p1 + 5*4096;         // 8192 floats, pair-major, all written every launch

  dim3 b(256,1,1);
  k_point_sobel<<<dim3(8, 32, 16), b, 0, stream>>>(vis, ir, fuse, p1);
  k_ssim<<<dim3(8, 16, 64), b, 0, stream>>>(vis, ir, fuse, p2);
  k_final<<<dim3(1,1,1), b, 0, stream>>>(p1, p2, out);
}